// Round 8
// baseline (62.353 us; speedup 1.0000x reference)
//
#include <hip/hip_runtime.h>

constexpr int M_ROWS = 16000;   // B*T
constexpr int DIM    = 512;
constexpr int NEXP   = 10;
constexpr int NSH    = 5;
constexpr int KTOP   = 5;

constexpr int TMA = 64;         // rows per gemm block
constexpr int NCB = 256;        // cols per gemm block (2 col-blocks)
constexpr int BK  = 32;         // k-tile
constexpr int NT  = DIM / BK;   // 16

constexpr int TMF = 32;         // rows per finalize block

typedef __attribute__((ext_vector_type(8))) short  bf16x8;
typedef __attribute__((ext_vector_type(4))) float  f32x4;

#define SB         __builtin_amdgcn_sched_barrier(0)
#define WAITVM(N)  do { asm volatile("s_waitcnt vmcnt(" #N ")" ::: "memory"); SB; } while (0)
#define WAITLGKM0  do { asm volatile("s_waitcnt lgkmcnt(0)" ::: "memory"); SB; } while (0)
#define BAR        do { __builtin_amdgcn_s_barrier(); SB; } while (0)

__device__ inline unsigned short bf16_rne(float x) {
    unsigned u = __float_as_uint(x);
    u += 0x7fffu + ((u >> 16) & 1u);
    return (unsigned short)(u >> 16);
}
__device__ inline float bf16_to_f(unsigned short h) {
    return __uint_as_float(((unsigned)h) << 16);
}

// ---------------- prep: W1 -> (hi,lo) bf16 [N][K]; shsum = sum_s shared_w ----
__global__ __launch_bounds__(256)
void prep_kernel(const float* __restrict__ W1, const float* __restrict__ shared_w,
                 unsigned short* __restrict__ w1hi, unsigned short* __restrict__ w1lo,
                 float* __restrict__ shsum)
{
    int b = blockIdx.x;
    if (b < 256) {
        int f = b * 256 + threadIdx.x;
        float4 v = *reinterpret_cast<const float4*>(&W1[(size_t)f * 4]);
        float xs[4] = {v.x, v.y, v.z, v.w};
        ushort4 h4, l4;
        unsigned short h[4], l[4];
        #pragma unroll
        for (int i = 0; i < 4; ++i) {
            h[i] = bf16_rne(xs[i]);
            float rem = xs[i] - bf16_to_f(h[i]);
            l[i] = bf16_rne(rem);
        }
        h4.x = h[0]; h4.y = h[1]; h4.z = h[2]; h4.w = h[3];
        l4.x = l[0]; l4.y = l[1]; l4.z = l[2]; l4.w = l[3];
        *reinterpret_cast<ushort4*>(&w1hi[(size_t)f * 4]) = h4;
        *reinterpret_cast<ushort4*>(&w1lo[(size_t)f * 4]) = l4;
    } else {
        for (int c = threadIdx.x; c < DIM; c += 256) {
            float s = 0.f;
            #pragma unroll
            for (int e = 0; e < NSH; ++e) s += shared_w[e * DIM + c];
            shsum[c] = s;
        }
    }
}

// ---------------- kernel A: GEMM + partial logits ----------------
// Geometry == round 7 (verified): 250x2 blocks, 512 thr = 8 waves, block
// 64r x 256c, wave (rgrp=wv>>2, cgrp=wv&3) = 32r x 64c, acc[2][4].
// LDS dbuf 2 x 40 KB; per buf (shorts): Bh[256][32] @0, Bl @8192,
// Ah[64][32] @16384, Al @18432. Chunk swizzle phys16B = logical^((row>>1)&3),
// applied pre-swizzled on gload_lds SOURCE + on reads (both-sides).
//
// NEW (T14+T4): counted-vmcnt pipeline, raw s_barrier, A-conversion deferred
// one full iteration (g(t+1) register-loaded at end of iter t-1, converted
// mid iter t). Steady in-flight bookkeeping (issue order pinned by SB):
//   top of iter t:      {g(t+1)}                        = 1
//   after stageB(t+1):  {g(t+1), B(t+1) x8}             = 9, g oldest
//   WAITVM(8)  -> g(t+1) landed; convert+write A(t+1)
//   issue g(t+2)        {B(t+1) x8, g(t+2)}             = 9, g newest
//   WAITVM(1)  -> B(t+1) landed; g(t+2) flies across BAR
// Logit tree BIT-EXACT vs rounds 4/6/7 (same MFMA shape/order, same chain,
// same butterfly, same w8 layout) -> absmax must reproduce 9.765625e-4.
__global__ __launch_bounds__(512, 4)
void gemm_logits(const float* __restrict__ G,
                 const unsigned short* __restrict__ w1hi,
                 const unsigned short* __restrict__ w1lo,
                 const float* __restrict__ W2,
                 float* __restrict__ plogG)
{
    __shared__ unsigned short smem[40960];   // 81920 B

    const int tid  = threadIdx.x;
    const int lane = tid & 63;
    const int wv   = tid >> 6;          // 0..7
    const int l15  = lane & 15;
    const int lg   = lane >> 4;
    const int rgrp = wv >> 2;           // 0..1
    const int cgrp = wv & 3;            // 0..3
    const int bx     = blockIdx.x;
    const int colblk = bx & 1;
    const int row0   = (bx >> 1) * TMA;
    const int cb     = colblk * NCB;

    // ---- hoisted per-thread addressing ----
    const int arow = tid >> 3;          // 0..63
    const int aq   = tid & 7;
    const int awoff = arow * 32 + ((aq >> 1) ^ ((arow >> 1) & 3)) * 8 + (aq & 1) * 4;
    const float* gp = &G[(size_t)(row0 + arow) * DIM + aq * 4];

    // B staging streams (r = 0,1): global srcs at k=0 (pre-swizzled) + LDS dests
    const unsigned short* bsrc_hi[2];
    const unsigned short* bsrc_lo[2];
    int bdst[2];
    #pragma unroll
    for (int r = 0; r < 2; ++r) {
        int f  = r * 512 + tid;          // 16B-chunk id, 0..1023
        int n  = f >> 2;                 // local col 0..255
        int js = (f & 3) ^ ((n >> 1) & 3);
        bsrc_hi[r] = w1hi + (size_t)(cb + n) * DIM + js * 8;
        bsrc_lo[r] = w1lo + (size_t)(cb + n) * DIM + js * 8;
        bdst[r]    = f * 8;              // shorts, within Bh region
    }

    // fragment LDS offsets (shorts, within a buf)
    int aoff[2], boff[4];
    #pragma unroll
    for (int rt = 0; rt < 2; ++rt) {
        int r_ = rgrp * 32 + rt * 16 + l15;
        aoff[rt] = 16384 + r_ * 32 + (lg ^ ((r_ >> 1) & 3)) * 8;
    }
    #pragma unroll
    for (int ct = 0; ct < 4; ++ct) {
        int n = cgrp * 64 + ct * 16 + l15;
        boff[ct] = n * 32 + (lg ^ ((n >> 1) & 3)) * 8;
    }

    f32x4 acc[2][4];
    #pragma unroll
    for (int rt = 0; rt < 2; ++rt)
        #pragma unroll
        for (int ct = 0; ct < 4; ++ct) acc[rt][ct] = (f32x4)0.f;

    auto stageB = [&](int t, int buf) {      // 8 gload_lds
        unsigned short* bb = smem + buf * 20480;
        #pragma unroll
        for (int r = 0; r < 2; ++r)
            __builtin_amdgcn_global_load_lds(
                (const __attribute__((address_space(1))) void*)(bsrc_hi[r] + t * BK),
                (__attribute__((address_space(3))) void*)(bb + bdst[r]), 16, 0, 0);
        #pragma unroll
        for (int r = 0; r < 2; ++r)
            __builtin_amdgcn_global_load_lds(
                (const __attribute__((address_space(1))) void*)(bsrc_lo[r] + t * BK),
                (__attribute__((address_space(3))) void*)(bb + 8192 + bdst[r]), 16, 0, 0);
    };
    auto writeA = [&](int buf, float4 g4) {
        float xs[4] = {g4.x, g4.y, g4.z, g4.w};
        unsigned short h[4], l[4];
        #pragma unroll
        for (int i = 0; i < 4; ++i) {
            h[i] = bf16_rne(xs[i]);
            float rem = xs[i] - bf16_to_f(h[i]);
            l[i] = bf16_rne(rem);
        }
        ushort4 h4, l4;
        h4.x = h[0]; h4.y = h[1]; h4.z = h[2]; h4.w = h[3];
        l4.x = l[0]; l4.y = l[1]; l4.z = l[2]; l4.w = l[3];
        unsigned short* ab = smem + buf * 20480 + awoff;
        *reinterpret_cast<ushort4*>(&ab[16384]) = h4;
        *reinterpret_cast<ushort4*>(&ab[18432]) = l4;
    };
    auto computeTile = [&](int buf) {
        const unsigned short* base = smem + buf * 20480;
        bf16x8 ah[2], al[2], bh[4], bl[4];
        #pragma unroll
        for (int rt = 0; rt < 2; ++rt) {
            ah[rt] = *reinterpret_cast<const bf16x8*>(&base[aoff[rt]]);
            al[rt] = *reinterpret_cast<const bf16x8*>(&base[aoff[rt] + 2048]);
        }
        #pragma unroll
        for (int ct = 0; ct < 4; ++ct) {
            bh[ct] = *reinterpret_cast<const bf16x8*>(&base[boff[ct]]);
            bl[ct] = *reinterpret_cast<const bf16x8*>(&base[boff[ct] + 8192]);
        }
        __builtin_amdgcn_s_setprio(1);
        // per-acc pass order (hh, lh, hl) == rounds 4/6/7 (bit-exact)
        #pragma unroll
        for (int ct = 0; ct < 4; ++ct)
            #pragma unroll
            for (int rt = 0; rt < 2; ++rt)
                acc[rt][ct] = __builtin_amdgcn_mfma_f32_16x16x32_bf16(ah[rt], bh[ct], acc[rt][ct], 0, 0, 0);
        #pragma unroll
        for (int ct = 0; ct < 4; ++ct)
            #pragma unroll
            for (int rt = 0; rt < 2; ++rt)
                acc[rt][ct] = __builtin_amdgcn_mfma_f32_16x16x32_bf16(al[rt], bh[ct], acc[rt][ct], 0, 0, 0);
        #pragma unroll
        for (int ct = 0; ct < 4; ++ct)
            #pragma unroll
            for (int rt = 0; rt < 2; ++rt)
                acc[rt][ct] = __builtin_amdgcn_mfma_f32_16x16x32_bf16(ah[rt], bl[ct], acc[rt][ct], 0, 0, 0);
        __builtin_amdgcn_s_setprio(0);
    };

    // ---- prologue ----
    float4 ga = *reinterpret_cast<const float4*>(gp);        // g(0), oldest
    SB;
    stageB(0, 0);                                            // +8 -> 9
    SB;
    WAITVM(8);                                               // g(0) landed
    writeA(0, ga);
    ga = *reinterpret_cast<const float4*>(gp + BK);          // g(1)
    WAITVM(1);                                               // B(0) landed
    WAITLGKM0;
    BAR;

    // ---- steady loop t = 0..NT-3 ----
    for (int t = 0; t < NT - 2; ++t) {
        const int cur = t & 1;
        stageB(t + 1, cur ^ 1);                              // {g(t+1), B x8}
        SB;
        computeTile(cur);
        WAITVM(8);                                           // g(t+1) landed
        writeA(cur ^ 1, ga);
        ga = *reinterpret_cast<const float4*>(gp + (t + 2) * BK);  // g(t+2)
        WAITVM(1);                                           // B(t+1) landed
        WAITLGKM0;
        BAR;
    }

    // ---- peeled iter t = NT-2 (no g(t+2)) ----
    {
        const int t = NT - 2;
        const int cur = t & 1;
        stageB(t + 1, cur ^ 1);
        SB;
        computeTile(cur);
        WAITVM(8);                                           // g(NT-1) landed
        writeA(cur ^ 1, ga);
        WAITVM(0);                                           // B(NT-1) landed
        WAITLGKM0;
        BAR;
    }

    // ---- tail t = NT-1 ----
    computeTile((NT - 1) & 1);

    // ---- ReLU ----
    #pragma unroll
    for (int rt = 0; rt < 2; ++rt)
        #pragma unroll
        for (int ct = 0; ct < 4; ++ct)
            #pragma unroll
            for (int j = 0; j < 4; ++j)
                acc[rt][ct][j] = fmaxf(acc[rt][ct][j], 0.f);

    // ---- per-wave 64-col logit partial (bit-exact tree) ----
    const int w8 = colblk * 4 + cgrp;
    #pragma unroll
    for (int e = 0; e < NEXP; ++e) {
        float w2v[4];
        #pragma unroll
        for (int ct = 0; ct < 4; ++ct)
            w2v[ct] = W2[(size_t)e * DIM + cb + cgrp * 64 + ct * 16 + l15];
        #pragma unroll
        for (int rt = 0; rt < 2; ++rt) {
            #pragma unroll
            for (int j = 0; j < 4; ++j) {
                float s = 0.f;
                #pragma unroll
                for (int ct = 0; ct < 4; ++ct)
                    s = fmaf(acc[rt][ct][j], w2v[ct], s);
                s += __shfl_xor(s, 1, 16);
                s += __shfl_xor(s, 2, 16);
                s += __shfl_xor(s, 4, 16);
                s += __shfl_xor(s, 8, 16);
                if (l15 == 0) {
                    int grow = row0 + rgrp * 32 + rt * 16 + lg * 4 + j;
                    plogG[((size_t)grow * 8 + w8) * NEXP + e] = s;
                }
            }
        }
    }
}

// ---------------- kernel B: reduce 8 partials + softmax/top-5 + output -----
__global__ __launch_bounds__(256)
void finalize(const float* __restrict__ plogG, const float* __restrict__ value,
              const float* __restrict__ shsum, const float* __restrict__ routing_w,
              float* __restrict__ out)
{
    __shared__ float swls[TMF * NEXP];
    const int tid  = threadIdx.x;
    const int row0 = blockIdx.x * TMF;

    if (tid < TMF) {
        const float* pr = &plogG[(size_t)(row0 + tid) * 8 * NEXP];
        float lgt[NEXP];
        #pragma unroll
        for (int e = 0; e < NEXP; ++e) lgt[e] = 0.f;
        #pragma unroll
        for (int w = 0; w < 8; ++w)        // sequential w-order (bit-exact)
            #pragma unroll
            for (int e = 0; e < NEXP; ++e)
                lgt[e] += pr[w * NEXP + e];

        float mx = lgt[0];
        #pragma unroll
        for (int e = 1; e < NEXP; ++e) mx = fmaxf(mx, lgt[e]);
        float p[NEXP], se = 0.f;
        #pragma unroll
        for (int e = 0; e < NEXP; ++e) { p[e] = expf(lgt[e] - mx); se += p[e]; }
        float inv = 1.f / se;
        #pragma unroll
        for (int e = 0; e < NEXP; ++e) p[e] *= inv;
        unsigned used = 0;
        #pragma unroll
        for (int t = 0; t < KTOP; ++t) {
            float bv = -1.f; int bi = 0;
            #pragma unroll
            for (int e = 0; e < NEXP; ++e) {
                bool better = (((used >> e) & 1u) == 0u) && (p[e] > bv);
                bv = better ? p[e] : bv;
                bi = better ? e : bi;
            }
            used |= 1u << bi;
        }
        #pragma unroll
        for (int e = 0; e < NEXP; ++e)
            swls[tid * NEXP + e] = ((used >> e) & 1u) ? p[e] : 0.f;
    }
    __syncthreads();

    const int c4 = (tid & 127) * 4;
    const int rh = tid >> 7;
    float4 sh4 = *reinterpret_cast<const float4*>(&shsum[c4]);
    float4 rw4[NEXP];
    #pragma unroll
    for (int e = 0; e < NEXP; ++e)
        rw4[e] = *reinterpret_cast<const float4*>(&routing_w[(size_t)e * DIM + c4]);
    #pragma unroll
    for (int r = 0; r < 16; ++r) {
        int row = rh * 16 + r;
        float val = value[row0 + row];
        float4 o = sh4;
        #pragma unroll
        for (int e = 0; e < NEXP; ++e) {
            float wgt = swls[row * NEXP + e];
            o.x = fmaf(wgt, rw4[e].x, o.x);
            o.y = fmaf(wgt, rw4[e].y, o.y);
            o.z = fmaf(wgt, rw4[e].z, o.z);
            o.w = fmaf(wgt, rw4[e].w, o.w);
        }
        o.x *= val; o.y *= val; o.z *= val; o.w *= val;
        *reinterpret_cast<float4*>(&out[(size_t)(row0 + row) * DIM + c4]) = o;
    }
}

extern "C" void kernel_launch(void* const* d_in, const int* in_sizes, int n_in,
                              void* d_out, int out_size, void* d_ws, size_t ws_size,
                              hipStream_t stream) {
    const float* G         = (const float*)d_in[0];
    const float* value     = (const float*)d_in[1];
    const float* shared_w  = (const float*)d_in[2];
    const float* routing_w = (const float*)d_in[3];
    const float* W1        = (const float*)d_in[4];
    const float* W2        = (const float*)d_in[5];
    float* out             = (float*)d_out;

    unsigned short* w1hi = (unsigned short*)d_ws;                        // 512 KB
    unsigned short* w1lo = (unsigned short*)((char*)d_ws + 524288);      // 512 KB
    float*          shs  = (float*)((char*)d_ws + 1048576);              // 2 KB
    float*          plg  = (float*)((char*)d_ws + 1056768);              // 5.12 MB [M][8][10]

    prep_kernel<<<257, 256, 0, stream>>>(W1, shared_w, w1hi, w1lo, shs);
    gemm_logits<<<(M_ROWS / TMA) * 2, 512, 0, stream>>>(G, w1hi, w1lo, W2, plg);
    finalize<<<M_ROWS / TMF, 256, 0, stream>>>(plg, value, shs, routing_w, out);
}